// Round 1
// baseline (651.873 us; speedup 1.0000x reference)
//
#include <hip/hip_runtime.h>
#include <math.h>

#define NB 16
#define TT 800
#define FF 90
#define SS 128
#define LL 200
#define NEGV (-1e30f)

// Forward kernel: blocks 0..15 = denominator FSA per utterance,
// blocks 16..31 = numerator chain per utterance.
// ws[0..15] = den scores, ws[16..31] = num scores.
__global__ __launch_bounds__(512) void mmi_forward(
    const float* __restrict__ x,          // N*T*F log-softmax
    const int*   __restrict__ sup,        // N*3 supervision segments
    const float* __restrict__ trans,      // S*S
    const int*   __restrict__ den_labels, // S
    const int*   __restrict__ num_labels, // N*L
    const int*   __restrict__ num_lens,   // N
    float*       __restrict__ ws)
{
    const int tid = threadIdx.x;
    __shared__ float sh_aexp[SS];        // exp(alpha - M), shifted linear domain
    __shared__ float sh_ypart[4 * SS];   // GEMV partials per chunk
    __shared__ float sh_xrow[FF];        // current frame's log-softmax row
    __shared__ float sh_wred[8];         // cross-wave reduction scratch
    __shared__ float sh_alpha[LL + 1];   // numerator chain state

    if (blockIdx.x < NB) {
        // ---------------- denominator ----------------
        const int n  = blockIdx.x;
        const int nf = sup[n * 3 + 2];
        const int s  = tid & (SS - 1);   // destination state
        const int c  = tid >> 7;         // source chunk 0..3 (32 sources each)

        // E = exp(trans) fragment held in registers: rows c*32..c*32+31, col s.
        float e[32];
        #pragma unroll
        for (int j = 0; j < 32; ++j)
            e[j] = __expf(trans[(c * 32 + j) * SS + s]);

        const int lab = (tid < SS) ? den_labels[s] : 0;

        if (tid < SS) sh_aexp[s] = (s == 0) ? 1.0f : 0.0f;  // exp(alpha0 - 0)
        float M = 0.0f;            // running max-shift (threads < SS)
        float alpha = (s == 0) ? 0.0f : NEGV;

        const float* xb = x + (size_t)n * TT * FF;
        float xreg = (tid < FF) ? xb[tid] : 0.0f;   // pipelined frame load

        for (int t = 0; t < nf; ++t) {
            __syncthreads();   // aexp(t) ready; prev xrow consumed
            if (tid < FF) {
                sh_xrow[tid] = xreg;
                if (t + 1 < nf) xreg = xb[(size_t)(t + 1) * FF + tid];
            }
            // linear-domain GEMV partial: p = sum_j aexp[c*32+j] * E[c*32+j][s]
            const float4* av = (const float4*)(sh_aexp + c * 32);
            float p = 0.0f;
            #pragma unroll
            for (int j = 0; j < 8; ++j) {
                float4 a4 = av[j];   // wave-uniform address -> LDS broadcast
                p += a4.x * e[4 * j] + a4.y * e[4 * j + 1] +
                     a4.z * e[4 * j + 2] + a4.w * e[4 * j + 3];
            }
            sh_ypart[c * SS + s] = p;
            __syncthreads();   // ypart + xrow ready
            if (tid < SS) {
                float y = sh_ypart[s] + sh_ypart[SS + s] +
                          sh_ypart[2 * SS + s] + sh_ypart[3 * SS + s];
                alpha = __logf(y) + M + sh_xrow[lab];
                // block max of alpha (2 waves)
                float m = alpha;
                #pragma unroll
                for (int off = 32; off > 0; off >>= 1)
                    m = fmaxf(m, __shfl_xor(m, off, 64));
                if ((tid & 63) == 0) sh_wred[tid >> 6] = m;
            }
            __syncthreads();   // wmax ready
            if (tid < SS) {
                float Mn = fmaxf(sh_wred[0], sh_wred[1]);
                sh_aexp[s] = __expf(alpha - Mn);
                M = Mn;
            }
        }
        __syncthreads();
        // den score = M + log(sum_s exp(alpha - M)) ; aexp already holds terms
        if (tid < SS) {
            float v = sh_aexp[s];
            #pragma unroll
            for (int off = 32; off > 0; off >>= 1)
                v += __shfl_xor(v, off, 64);
            if ((tid & 63) == 0) sh_wred[2 + (tid >> 6)] = v;
        }
        __syncthreads();
        if (tid == 0) ws[n] = M + __logf(sh_wred[2] + sh_wred[3]);
    } else {
        // ---------------- numerator ----------------
        const int n  = blockIdx.x - NB;
        const int nf = sup[n * 3 + 2];
        const int lab = (tid < LL) ? num_labels[n * LL + tid] : 0;
        if (tid <= LL) sh_alpha[tid] = (tid == 0) ? 0.0f : NEGV;

        const float* xb = x + (size_t)n * TT * FF;
        float xreg = (tid < FF) ? xb[tid] : 0.0f;

        for (int t = 0; t < nf; ++t) {
            __syncthreads();   // alpha(t) writes done; prev xrow consumed
            float a = 0.0f, b = 0.0f;
            if (tid < FF) {
                sh_xrow[tid] = xreg;
                if (t + 1 < nf) xreg = xb[(size_t)(t + 1) * FF + tid];
            }
            if (tid < LL) { a = sh_alpha[tid]; b = sh_alpha[tid + 1]; }
            __syncthreads();   // xrow ready; alpha reads done
            if (tid < LL) {
                float m = fmaxf(a, b);
                float d = fminf(a, b) - m;
                sh_alpha[tid + 1] = m + log1pf(__expf(d)) + sh_xrow[lab];
            }
            if (tid == LL) sh_alpha[0] = NEGV;
        }
        __syncthreads();
        if (tid == 0) ws[NB + n] = sh_alpha[num_lens[n]];
    }
}

__global__ void mmi_finalize(const float* __restrict__ ws,
                             const int* __restrict__ sup,
                             float* __restrict__ out)
{
    const int tid = threadIdx.x;  // 64 threads
    float tot_score = 0.0f, tot_frames = 0.0f, all_frames = 0.0f;
    if (tid < NB) {
        float tot = ws[NB + tid] - ws[tid];   // num - den (DEN_SCALE=1)
        int nf = sup[tid * 3 + 2];
        bool fin = isfinite(tot) && (tot > 0.5f * NEGV);
        tot_score  = fin ? tot : 0.0f;
        tot_frames = fin ? (float)nf : 0.0f;
        all_frames = (float)nf;
    }
    #pragma unroll
    for (int off = 32; off > 0; off >>= 1) {
        tot_score  += __shfl_xor(tot_score, off, 64);
        tot_frames += __shfl_xor(tot_frames, off, 64);
        all_frames += __shfl_xor(all_frames, off, 64);
    }
    if (tid == 0) {
        out[0] = tot_score;
        out[1] = tot_frames;
        out[2] = all_frames;
    }
}

extern "C" void kernel_launch(void* const* d_in, const int* in_sizes, int n_in,
                              void* d_out, int out_size, void* d_ws, size_t ws_size,
                              hipStream_t stream) {
    const float* x          = (const float*)d_in[0];
    const int*   sup        = (const int*)d_in[1];
    const float* trans      = (const float*)d_in[2];
    const int*   den_labels = (const int*)d_in[3];
    const int*   num_labels = (const int*)d_in[4];
    const int*   num_lens   = (const int*)d_in[5];
    float* ws  = (float*)d_ws;
    float* out = (float*)d_out;

    mmi_forward<<<dim3(32), dim3(512), 0, stream>>>(
        x, sup, trans, den_labels, num_labels, num_lens, ws);
    mmi_finalize<<<dim3(1), dim3(64), 0, stream>>>(ws, sup, out);
}

// Round 2
// 370.561 us; speedup vs baseline: 1.7592x; 1.7592x over previous
//
#include <hip/hip_runtime.h>
#include <math.h>

#define NB 16
#define TT 800
#define FF 90
#define SS 128
#define LL 200
#define NEGV (-1e30f)

// blocks 0..15: denominator FSA (linear-domain scaled forward, renorm every 16 steps)
// blocks 16..31: numerator chain (log-domain, double-buffered)
// ws[0..15] = den scores, ws[16..31] = num scores
__global__ __launch_bounds__(256) void mmi_forward(
    const float* __restrict__ x,          // N*T*F log-softmax
    const int*   __restrict__ sup,        // N*3
    const float* __restrict__ trans,      // S*S
    const int*   __restrict__ den_labels, // S
    const int*   __restrict__ num_labels, // N*L
    const int*   __restrict__ num_lens,   // N
    float*       __restrict__ ws)
{
    const int tid = threadIdx.x;
    __shared__ float sh_v[SS];           // scaled linear alphas
    __shared__ float sh_part[8 * SS];    // chunk partials: part[c][d]
    __shared__ float sh_red[4];
    __shared__ float sh_na[2][LL + 4];   // num alpha double buffer

    if (blockIdx.x < NB) {
        // ---------------- denominator ----------------
        const int n  = blockIdx.x;
        const int nf = sup[n * 3 + 2];
        const int g  = tid & 31;   // dest group: dests 4g..4g+3
        const int c  = tid >> 5;   // source chunk: srcs 16c..16c+15

        // E fragment in registers: E[16c+j][4g+dd], 64 floats/thread
        float4 e[16];
        #pragma unroll
        for (int j = 0; j < 16; ++j) {
            const float4 t4 = *(const float4*)(trans + (size_t)(16 * c + j) * SS + 4 * g);
            e[j] = make_float4(__expf(t4.x), __expf(t4.y), __expf(t4.z), __expf(t4.w));
        }

        const float* xb = x + (size_t)n * TT * FF;
        int lab = 0;
        float xn = 0.0f, pe = 0.0f, logM = 0.0f, v = 0.0f;
        if (tid < SS) {
            lab = den_labels[tid];
            sh_v[tid] = (tid == 0) ? 1.0f : 0.0f;
            xn = xb[lab];   // raw log-emit for t=0
        }
        __syncthreads();

        for (int t = 0; t < nf; ++t) {
            // ---- phase A: GEMV partials; prefetch next emit off-chain ----
            if (tid < SS) {
                pe = __expf(xn);
                const int t1 = (t + 1 < nf) ? (t + 1) : t;
                xn = xb[(size_t)t1 * FF + lab];
            }
            float4 aa[4];
            {
                const float4* av = (const float4*)(sh_v + 16 * c);
                aa[0] = av[0]; aa[1] = av[1]; aa[2] = av[2]; aa[3] = av[3];
            }
            const float* as = (const float*)aa;
            float4 acc = make_float4(0.f, 0.f, 0.f, 0.f);
            #pragma unroll
            for (int j = 0; j < 16; ++j) {
                acc.x = fmaf(as[j], e[j].x, acc.x);
                acc.y = fmaf(as[j], e[j].y, acc.y);
                acc.z = fmaf(as[j], e[j].z, acc.z);
                acc.w = fmaf(as[j], e[j].w, acc.w);
            }
            *(float4*)(sh_part + c * SS + 4 * g) = acc;
            __syncthreads();   // partials ready

            // ---- phase B: reduce 8 chunks, apply emission, periodic renorm ----
            const bool rs = ((t & 15) == 15);
            if (tid < SS) {
                float y = 0.0f;
                #pragma unroll
                for (int cc = 0; cc < 8; ++cc) y += sh_part[cc * SS + tid];
                v = y * pe;
                if (rs) {
                    float m = v;
                    #pragma unroll
                    for (int off = 32; off >= 1; off >>= 1)
                        m = fmaxf(m, __shfl_xor(m, off, 64));
                    if ((tid & 63) == 0) sh_red[tid >> 6] = m;
                }
            }
            if (rs) {
                __syncthreads();
                if (tid < SS) {
                    float mm = fmaxf(sh_red[0], sh_red[1]);
                    mm = fmaxf(mm, 1e-37f);
                    v *= (1.0f / mm);
                    logM += __logf(mm);
                }
            }
            if (tid < SS) sh_v[tid] = v;
            __syncthreads();   // alphas ready for next step; part WAR
        }

        // den score = logM + log(sum_s v[s])
        if (tid < SS) {
            float ssum = v;
            #pragma unroll
            for (int off = 32; off >= 1; off >>= 1)
                ssum += __shfl_xor(ssum, off, 64);
            if ((tid & 63) == 0) sh_red[2 + (tid >> 6)] = ssum;
        }
        __syncthreads();
        if (tid == 0) ws[n] = logM + __logf(sh_red[2] + sh_red[3]);
    } else {
        // ---------------- numerator (log domain, double-buffered) ----------------
        const int n  = blockIdx.x - NB;
        const int nf = sup[n * 3 + 2];
        const float* xb = x + (size_t)n * TT * FF;
        int lab = 0;
        float en = 0.0f;
        if (tid < LL) {
            lab = num_labels[n * LL + tid];
            en  = xb[lab];   // raw log-emit for t=0
        }
        if (tid <= LL) sh_na[0][tid] = (tid == 0) ? 0.0f : NEGV;
        int p = 0;
        __syncthreads();

        for (int t = 0; t < nf; ++t) {
            float a = 0.f, b = 0.f, ec = 0.f;
            if (tid < LL) {
                a  = sh_na[p][tid];
                b  = sh_na[p][tid + 1];
                ec = en;
                const int t1 = (t + 1 < nf) ? (t + 1) : t;
                en = xb[(size_t)t1 * FF + lab];
            }
            if (tid < LL) {
                float m = fmaxf(a, b);
                float d = fminf(a, b) - m;
                sh_na[p ^ 1][tid + 1] = m + log1pf(__expf(d)) + ec;
            }
            if (tid == LL) sh_na[p ^ 1][0] = NEGV;
            p ^= 1;
            __syncthreads();   // new buffer ready
        }
        if (tid == 0) ws[NB + n] = sh_na[p][num_lens[n]];
    }
}

__global__ void mmi_finalize(const float* __restrict__ ws,
                             const int* __restrict__ sup,
                             float* __restrict__ out)
{
    const int tid = threadIdx.x;  // 64 threads
    float tot_score = 0.0f, tot_frames = 0.0f, all_frames = 0.0f;
    if (tid < NB) {
        float tot = ws[NB + tid] - ws[tid];   // num - den (DEN_SCALE=1)
        int nf = sup[tid * 3 + 2];
        bool fin = isfinite(tot) && (tot > 0.5f * NEGV);
        tot_score  = fin ? tot : 0.0f;
        tot_frames = fin ? (float)nf : 0.0f;
        all_frames = (float)nf;
    }
    #pragma unroll
    for (int off = 32; off >= 1; off >>= 1) {
        tot_score  += __shfl_xor(tot_score, off, 64);
        tot_frames += __shfl_xor(tot_frames, off, 64);
        all_frames += __shfl_xor(all_frames, off, 64);
    }
    if (tid == 0) {
        out[0] = tot_score;
        out[1] = tot_frames;
        out[2] = all_frames;
    }
}

extern "C" void kernel_launch(void* const* d_in, const int* in_sizes, int n_in,
                              void* d_out, int out_size, void* d_ws, size_t ws_size,
                              hipStream_t stream) {
    const float* x          = (const float*)d_in[0];
    const int*   sup        = (const int*)d_in[1];
    const float* trans      = (const float*)d_in[2];
    const int*   den_labels = (const int*)d_in[3];
    const int*   num_labels = (const int*)d_in[4];
    const int*   num_lens   = (const int*)d_in[5];
    float* ws  = (float*)d_ws;
    float* out = (float*)d_out;

    mmi_forward<<<dim3(32), dim3(256), 0, stream>>>(
        x, sup, trans, den_labels, num_labels, num_lens, ws);
    mmi_finalize<<<dim3(1), dim3(64), 0, stream>>>(ws, sup, out);
}